// Round 2
// baseline (6525.217 us; speedup 1.0000x reference)
//
#include <hip/hip_runtime.h>
#include <cstdint>

// Problem constants (fixed by the reference).
namespace {
constexpr int B = 4, T = 8192, C = 128, R = 64, S = 256, SO = 256, O = 256, L = 16;
constexpr float SQRT_HALF = 0.70710678118654752440f;
}

__device__ __forceinline__ float fsigm(float x) { return 1.0f / (1.0f + __expf(-x)); }
__device__ __forceinline__ float ftanh(float x) { return 1.0f - 2.0f / (1.0f + __expf(2.0f * x)); }

// Wave-uniform pin so weight rows select s_load and FMAs take SGPR operands.
__device__ __forceinline__ int uni(int v) { return __builtin_amdgcn_readfirstlane(v); }

// x[b,r,t] = embed[tokens[b,t], r]
__global__ __launch_bounds__(256) void k_embed(const int* __restrict__ tokens,
                                               const float* __restrict__ embed,
                                               float* __restrict__ x) {
  int blk = blockIdx.x;            // B * (T/64) = 512
  int b = blk >> 7;
  int t0 = (blk & 127) << 6;
  int lane = threadIdx.x & 63;
  int w = threadIdx.x >> 6;        // wave handles 16 r's
  int t = t0 + lane;
  int tok = tokens[b * T + t];
  const float* e = embed + tok * R + w * 16;
  float* xp = x + ((size_t)b * R + w * 16) * T + t;
#pragma unroll
  for (int j = 0; j < 16; ++j) xp[(size_t)j * T] = e[j];
}

// cond[b, o, t] = cond_W[o,:] . features[b,:,t] + cond_b[o]   (o in [0,2048))
// Features tile staged cooperatively in LDS (kills 4x redundant loads).
__global__ __launch_bounds__(256) void k_cond(const float* __restrict__ feat,
                                              const float* __restrict__ condW,
                                              const float* __restrict__ condb,
                                              float* __restrict__ cond_out) {
  __shared__ float fs[C][64];      // 32 KB
  int blk = blockIdx.x;            // 512
  int b = blk >> 7;
  int t0 = (blk & 127) << 6;
  int lane = threadIdx.x & 63;
  int w = threadIdx.x >> 6;
  int oc = blockIdx.y;             // 8 chunks of 256 outputs
  int o0 = uni(oc * 256 + w * 64); // this thread: 64 outputs (wave-uniform)
  int cs = uni(w * 32);            // staging channel base
  int t = t0 + lane;
  const float* fb = feat + (size_t)b * C * T + t;
#pragma unroll
  for (int j = 0; j < 32; ++j) fs[cs + j][lane] = fb[(size_t)(cs + j) * T];
  __syncthreads();
  float acc[64];
#pragma unroll
  for (int j = 0; j < 64; ++j) acc[j] = condb[o0 + j];
  for (int kc = 0; kc < 8; ++kc) {   // k-chunks of 16; per-j order still k=0..127
    float areg[16];
#pragma unroll
    for (int k = 0; k < 16; ++k) areg[k] = fs[kc * 16 + k][lane];
#pragma unroll
    for (int j = 0; j < 64; ++j) {
      const float* wr = condW + (size_t)(o0 + j) * C + kc * 16;  // uniform -> s_load
      float a = acc[j];
#pragma unroll
      for (int k = 0; k < 16; ++k) a = fmaf(wr[k], areg[k], a);
      acc[j] = a;
    }
  }
  float* outp = cond_out + ((size_t)b * (2 * R * L) + o0) * T + t;
#pragma unroll
  for (int j = 0; j < 64; ++j) outp[(size_t)j * T] = acc[j];
}

// One WaveNet layer: ia = W0 x[t-d] + W1 x[t] + b (written to d_out),
// acts = tanh(.)*sigm(.), x_out = (res_W acts + res_b + x) * sqrt(0.5).
// x tiles staged cooperatively in LDS; cond prefetched into regs at top.
__global__ __launch_bounds__(256) void k_layer(const float* __restrict__ x_in,
                                               float* __restrict__ x_out,
                                               const float* __restrict__ cond,
                                               const float* __restrict__ dW,   // (128,64,2)
                                               const float* __restrict__ db,   // (128)
                                               const float* __restrict__ resW, // (64,64)
                                               const float* __restrict__ resb, // (64)
                                               float* __restrict__ ia_out,
                                               int l, int d, int last) {
  __shared__ float xs[64][64];     // x[:, t]        16 KB
  __shared__ float xps[64][64];    // x[:, t-d]      16 KB
  __shared__ float acts[64][64];   //                16 KB
  int blk = blockIdx.x;            // 512
  int b = blk >> 7;
  int t0 = (blk & 127) << 6;
  int lane = threadIdx.x & 63;
  int w = threadIdx.x >> 6;
  int t = t0 + lane;
  int p0 = uni(w * 16);            // wave-uniform gate-pair base
  const float* xb = x_in + (size_t)b * R * T;
  // cond prefetch (consumed after the ia FMA block ~9K cycles later)
  const float* cnd = cond + (size_t)(b * L + l) * 128 * T + t;
  float c1[16], c2[16];
#pragma unroll
  for (int j = 0; j < 16; ++j) {
    c1[j] = cnd[(size_t)(p0 + j) * T];
    c2[j] = cnd[(size_t)(p0 + j + 64) * T];
  }
  // cooperative x staging (each wave stages 16 channels, not all 64)
#pragma unroll
  for (int j = 0; j < 16; ++j) {
    int ch = p0 + j;               // p0 = w*16 -> ch covers 0..63 across waves
    xs[ch][lane] = xb[(size_t)ch * T + t];
    xps[ch][lane] = (t >= d) ? xb[(size_t)ch * T + t - d] : 0.0f;
  }
  __syncthreads();
  // ia FMA: chunked k (order per output still k=0..63, taps interleaved as before)
  float a1[16], a2[16];
#pragma unroll
  for (int j = 0; j < 16; ++j) { a1[j] = db[p0 + j]; a2[j] = db[p0 + j + 64]; }
#pragma unroll
  for (int kc = 0; kc < 4; ++kc) {
    float xcr[16], xpr[16];
#pragma unroll
    for (int k = 0; k < 16; ++k) {
      xcr[k] = xs[kc * 16 + k][lane];
      xpr[k] = xps[kc * 16 + k][lane];
    }
#pragma unroll
    for (int j = 0; j < 16; ++j) {
      const float* w1 = dW + (size_t)(p0 + j) * 128 + kc * 32;       // uniform -> s_load
      const float* w2 = dW + (size_t)(p0 + j + 64) * 128 + kc * 32;
      float s1 = a1[j], s2 = a2[j];
#pragma unroll
      for (int k = 0; k < 16; ++k) {
        s1 = fmaf(w1[2 * k], xpr[k], s1);
        s1 = fmaf(w1[2 * k + 1], xcr[k], s1);
        s2 = fmaf(w2[2 * k], xpr[k], s2);
        s2 = fmaf(w2[2 * k + 1], xcr[k], s2);
      }
      a1[j] = s1; a2[j] = s2;
    }
  }
  float* iao = ia_out + (size_t)(b * L + l) * 128 * T + t;
#pragma unroll
  for (int j = 0; j < 16; ++j) {
    iao[(size_t)(p0 + j) * T] = a1[j];
    iao[(size_t)(p0 + j + 64) * T] = a2[j];
  }
#pragma unroll
  for (int j = 0; j < 16; ++j) {
    float g1 = a1[j] + c1[j];
    float g2 = a2[j] + c2[j];
    acts[p0 + j][lane] = ftanh(g1) * fsigm(g2);
  }
  __syncthreads();
  if (!last) {
    float racc[16];
#pragma unroll
    for (int j = 0; j < 16; ++j) racc[j] = resb[p0 + j];
#pragma unroll
    for (int kc = 0; kc < 4; ++kc) {
      float areg[16];
#pragma unroll
      for (int k = 0; k < 16; ++k) areg[k] = acts[kc * 16 + k][lane];
#pragma unroll
      for (int j = 0; j < 16; ++j) {
        const float* wr = resW + (size_t)(p0 + j) * R + kc * 16;     // uniform -> s_load
        float a = racc[j];
#pragma unroll
        for (int k = 0; k < 16; ++k) a = fmaf(wr[k], areg[k], a);
        racc[j] = a;
      }
    }
    float* xo = x_out + (size_t)b * R * T + t;
#pragma unroll
    for (int j = 0; j < 16; ++j) {
      xo[(size_t)(p0 + j) * T] = (racc[j] + xs[p0 + j][lane]) * SQRT_HALF;
    }
  }
}

// skip_out[b,s,t] = sum_l ( skip_W[l,s,:] . acts_l[:,t] + skip_b[l,s] )
// Software-pipelined: stage ia(l) in LDS (double-buffered), gates computed
// cooperatively ONCE per block into LDS; layer l+1's loads issue during
// layer l's FMA block (issue-early / write-late).
__global__ __launch_bounds__(256) void k_skip(const float* __restrict__ ia,
                                              const float* __restrict__ cond,
                                              const float* __restrict__ skipW, // (L,256,64)
                                              const float* __restrict__ skipb, // (L,256)
                                              float* __restrict__ skip_out) {
  __shared__ float raw[2][128][64];  // 64 KB: staged ia double buffer
  __shared__ float acts[64][64];     // 16 KB: gates
  int blk = blockIdx.x;              // 512
  int b = blk >> 7;
  int t0 = (blk & 127) << 6;
  int lane = threadIdx.x & 63;
  int w = threadIdx.x >> 6;
  int t = t0 + lane;
  int s0 = uni(w * 64);              // 64 skip channels per thread
  int kg = uni(w * 16);              // gate base for this wave
  int cs = uni(w * 32);              // staging channel base

  float acc[64];
#pragma unroll
  for (int j = 0; j < 64; ++j) {
    float bs = 0.0f;
    for (int l = 0; l < L; ++l) bs += skipb[l * S + s0 + j];
    acc[j] = bs;
  }

  const float* iab0 = ia + (size_t)(b * L) * 128 * T + t;
  const float* cnb0 = cond + (size_t)(b * L) * 128 * T + t;

  // prologue: stage layer 0 ia + load layer 0 cond
  float sreg[32], c1[16], c2[16];
#pragma unroll
  for (int j = 0; j < 32; ++j) sreg[j] = iab0[(size_t)(cs + j) * T];
#pragma unroll
  for (int j = 0; j < 16; ++j) {
    c1[j] = cnb0[(size_t)(kg + j) * T];
    c2[j] = cnb0[(size_t)(kg + j + 64) * T];
  }
#pragma unroll
  for (int j = 0; j < 32; ++j) raw[0][cs + j][lane] = sreg[j];

  int cur = 0;
  for (int l = 0; l < L; ++l) {
    __syncthreads();                 // raw[cur] staged; prior FMA done with acts
    // gates (cooperative, once per block): all LDS reads 2-way bank (free)
#pragma unroll
    for (int j = 0; j < 16; ++j) {
      float g1 = raw[cur][kg + j][lane] + c1[j];
      float g2 = raw[cur][kg + j + 64][lane] + c2[j];
      acts[kg + j][lane] = ftanh(g1) * fsigm(g2);
    }
    __syncthreads();                 // acts visible
    // prefetch layer l+1 while FMA-ing layer l (c1/c2 dead after gates)
    if (l + 1 < L) {
      const float* iab = iab0 + (size_t)(l + 1) * 128 * T;
      const float* cnb = cnb0 + (size_t)(l + 1) * 128 * T;
#pragma unroll
      for (int j = 0; j < 32; ++j) sreg[j] = iab[(size_t)(cs + j) * T];
#pragma unroll
      for (int j = 0; j < 16; ++j) {
        c1[j] = cnb[(size_t)(kg + j) * T];
        c2[j] = cnb[(size_t)(kg + j + 64) * T];
      }
    }
    // FMA block: per-j accumulation order still k = 0..63 sequential
    const float* sw = skipW + (size_t)l * S * R + (size_t)s0 * R;
#pragma unroll
    for (int kc = 0; kc < 4; ++kc) {
      float areg[16];
#pragma unroll
      for (int k = 0; k < 16; ++k) areg[k] = acts[kc * 16 + k][lane];
#pragma unroll
      for (int j = 0; j < 64; ++j) {
        const float* wr = sw + (size_t)j * R + kc * 16;              // uniform -> s_load
        float a = acc[j];
#pragma unroll
        for (int k = 0; k < 16; ++k) a = fmaf(wr[k], areg[k], a);
        acc[j] = a;
      }
    }
    // write-late: loads have had the whole FMA block to land
    if (l + 1 < L) {
#pragma unroll
      for (int j = 0; j < 32; ++j) raw[cur ^ 1][cs + j][lane] = sreg[j];
      cur ^= 1;
    }
  }
  float* sp = skip_out + ((size_t)b * S + s0) * T + t;
#pragma unroll
  for (int j = 0; j < 64; ++j) sp[(size_t)j * T] = acc[j];
}

// out = shift_right( Wend @ relu( Wout @ relu(skip) ) )
// relu(skip) tile staged cooperatively (64 KB), buffer reused for hidden.
__global__ __launch_bounds__(256) void k_head(const float* __restrict__ skip_in,
                                              const float* __restrict__ Wout, // (256,256)
                                              const float* __restrict__ Wend, // (256,256)
                                              float* __restrict__ out) {
  __shared__ float ss[SO][64];     // 64 KB: relu(skip), then reused as hidden
  int blk = blockIdx.x;            // 512
  int b = blk >> 7;
  int t0 = (blk & 127) << 6;
  int lane = threadIdx.x & 63;
  int w = threadIdx.x >> 6;
  int t = t0 + lane;
  int g0 = uni(w * 64);            // 64 outputs of each stage per thread
  const float* sp = skip_in + (size_t)b * S * T + t;
#pragma unroll
  for (int j = 0; j < 64; ++j)
    ss[g0 + j][lane] = fmaxf(sp[(size_t)(g0 + j) * T], 0.0f);
  __syncthreads();
  float acc[64];
#pragma unroll
  for (int j = 0; j < 64; ++j) acc[j] = 0.0f;
  for (int kc = 0; kc < 16; ++kc) {   // per-j order still k = 0..255
    float areg[16];
#pragma unroll
    for (int k = 0; k < 16; ++k) areg[k] = ss[kc * 16 + k][lane];
#pragma unroll
    for (int j = 0; j < 64; ++j) {
      const float* wr = Wout + (size_t)(g0 + j) * S + kc * 16;       // uniform -> s_load
      float a = acc[j];
#pragma unroll
      for (int k = 0; k < 16; ++k) a = fmaf(wr[k], areg[k], a);
      acc[j] = a;
    }
  }
  __syncthreads();                 // all reads of ss complete
#pragma unroll
  for (int j = 0; j < 64; ++j) ss[g0 + j][lane] = fmaxf(acc[j], 0.0f);
  __syncthreads();
#pragma unroll
  for (int j = 0; j < 64; ++j) acc[j] = 0.0f;
  for (int kc = 0; kc < 16; ++kc) {
    float areg[16];
#pragma unroll
    for (int k = 0; k < 16; ++k) areg[k] = ss[kc * 16 + k][lane];
#pragma unroll
    for (int j = 0; j < 64; ++j) {
      const float* wr = Wend + (size_t)(g0 + j) * SO + kc * 16;      // uniform -> s_load
      float a = acc[j];
#pragma unroll
      for (int k = 0; k < 16; ++k) a = fmaf(wr[k], areg[k], a);
      acc[j] = a;
    }
  }
  float* ob = out + ((size_t)b * O + g0) * T;
  if (t + 1 < T) {
#pragma unroll
    for (int j = 0; j < 64; ++j) ob[(size_t)j * T + t + 1] = acc[j];
  }
  if (t0 == 0 && lane == 0) {      // zero frame at t=0
#pragma unroll
    for (int j = 0; j < 64; ++j) ob[(size_t)j * T] = 0.0f;
  }
}

extern "C" void kernel_launch(void* const* d_in, const int* in_sizes, int n_in,
                              void* d_out, int out_size, void* d_ws, size_t ws_size,
                              hipStream_t stream) {
  const float* features   = (const float*)d_in[0];
  const int*   tokens     = (const int*)d_in[1];
  const float* embed      = (const float*)d_in[2];
  const float* cond_W     = (const float*)d_in[3];
  const float* cond_b     = (const float*)d_in[4];
  const float* dilate_W   = (const float*)d_in[5];
  const float* dilate_b   = (const float*)d_in[6];
  const float* res_W      = (const float*)d_in[7];
  const float* res_b      = (const float*)d_in[8];
  const float* skip_W     = (const float*)d_in[9];
  const float* skip_b     = (const float*)d_in[10];
  const float* conv_out_W = (const float*)d_in[11];
  const float* conv_end_W = (const float*)d_in[12];

  // d_out regions: out (B*O*T), in_acts (B*L*128*T), cond (B*L*128*T)
  float* out  = (float*)d_out;
  float* ia   = out + (size_t)B * O * T;
  float* cond = ia + (size_t)B * L * 2 * R * T;

  // workspace: x ping-pong (2 x 8 MB) + skip_out (32 MB) = 48 MB
  float* xa   = (float*)d_ws;
  float* xb   = xa + (size_t)B * R * T;
  float* skip = xb + (size_t)B * R * T;

  dim3 blk(256);
  int nblk = B * (T / 64);  // 512

  k_embed<<<nblk, blk, 0, stream>>>(tokens, embed, xa);
  k_cond<<<dim3(nblk, 8), blk, 0, stream>>>(features, cond_W, cond_b, cond);

  static const int DIL[L] = {1, 2, 4, 8, 16, 32, 64, 128, 256, 1, 2, 4, 8, 16, 32, 64};
  float* xcur = xa;
  float* xnxt = xb;
  for (int l = 0; l < L; ++l) {
    int lr = (l < L - 1) ? l : 0;  // resW/resb unused when last
    k_layer<<<nblk, blk, 0, stream>>>(xcur, xnxt, cond,
                                      dilate_W + (size_t)l * 128 * 64 * 2,
                                      dilate_b + (size_t)l * 128,
                                      res_W + (size_t)lr * 64 * 64,
                                      res_b + (size_t)lr * 64,
                                      ia, l, DIL[l], (l == L - 1) ? 1 : 0);
    float* tmp = xcur; xcur = xnxt; xnxt = tmp;
  }
  k_skip<<<nblk, blk, 0, stream>>>(ia, cond, skip_W, skip_b, skip);
  k_head<<<nblk, blk, 0, stream>>>(skip, conv_out_W, conv_end_W, out);
}